// Round 1
// baseline (826.564 us; speedup 1.0000x reference)
//
#include <hip/hip_runtime.h>
#include <math.h>

#define HN 16
#define SEQ 1024
#define DMODEL 1024
#define DH 64
#define SM1 1023   // S-1

// ---------------------------------------------------------------
// Kernel A/D: fp32 GEMM  out = X @ W + bias
// MODE 0: head-split output  out[((b*HN+h)*rows + s)*64 + dh]
// MODE 1: plain output       out[m*1024 + n]
// BM=BN=64, BK=16, 256 threads, 4x4 per thread.
// ---------------------------------------------------------------
template<int MODE>
__global__ __launch_bounds__(256)
void gemm64_kernel(const float* __restrict__ X, const float* __restrict__ W,
                   const float* __restrict__ bias, float* __restrict__ out,
                   int M, int rows)
{
    __shared__ float As[16][68];
    __shared__ float Bs[16][68];
    const int t  = threadIdx.x;
    const int tx = t & 15, ty = t >> 4;
    const int m0 = blockIdx.y * 64, n0 = blockIdx.x * 64;
    const int arow = t >> 2, aq = t & 3;
    const int brow = t >> 4, bq4 = t & 15;

    float acc[4][4] = {};

    for (int k0 = 0; k0 < DMODEL; k0 += 16) {
        __syncthreads();
        float4 av = {0.f, 0.f, 0.f, 0.f};
        if (m0 + arow < M)
            av = *(const float4*)&X[(size_t)(m0 + arow) * DMODEL + k0 + aq * 4];
        As[aq * 4 + 0][arow] = av.x;
        As[aq * 4 + 1][arow] = av.y;
        As[aq * 4 + 2][arow] = av.z;
        As[aq * 4 + 3][arow] = av.w;
        float4 bv = *(const float4*)&W[(size_t)(k0 + brow) * DMODEL + n0 + bq4 * 4];
        *(float4*)&Bs[brow][bq4 * 4] = bv;
        __syncthreads();

#pragma unroll
        for (int kk = 0; kk < 16; ++kk) {
            float4 a = *(const float4*)&As[kk][ty * 4];
            float4 b = *(const float4*)&Bs[kk][tx * 4];
            acc[0][0] += a.x * b.x; acc[0][1] += a.x * b.y; acc[0][2] += a.x * b.z; acc[0][3] += a.x * b.w;
            acc[1][0] += a.y * b.x; acc[1][1] += a.y * b.y; acc[1][2] += a.y * b.z; acc[1][3] += a.y * b.w;
            acc[2][0] += a.z * b.x; acc[2][1] += a.z * b.y; acc[2][2] += a.z * b.z; acc[2][3] += a.z * b.w;
            acc[3][0] += a.w * b.x; acc[3][1] += a.w * b.y; acc[3][2] += a.w * b.z; acc[3][3] += a.w * b.w;
        }
    }

    float4 b4 = *(const float4*)&bias[n0 + tx * 4];
#pragma unroll
    for (int i = 0; i < 4; ++i) {
        int m = m0 + ty * 4 + i;
        if (m >= M) continue;
        float4 o;
        o.x = acc[i][0] + b4.x; o.y = acc[i][1] + b4.y;
        o.z = acc[i][2] + b4.z; o.w = acc[i][3] + b4.w;
        if (MODE == 0) {
            int bb = m / rows, s = m % rows;
            int h  = n0 >> 6;
            *(float4*)&out[(((size_t)(bb * HN + h) * rows + s) << 6) + tx * 4] = o;
        } else {
            *(float4*)&out[(size_t)m * DMODEL + n0 + tx * 4] = o;
        }
    }
}

// ---------------------------------------------------------------
// Kernel B: scores = relu((qh[1:] @ kh[:-1]^T)/8) - 1e9*mask
// Tile: 32 q-rows x 1023 keys per block, 128-key LDS tiles.
// Writes masked logits (fp32) into att region of d_out.
// ---------------------------------------------------------------
__global__ __launch_bounds__(256)
void qk_kernel(const float* __restrict__ qh, const float* __restrict__ kh,
               const int* __restrict__ mask, float* __restrict__ att)
{
    __shared__ float qs[32 * 68];
    __shared__ float ks[128 * 64];   // XOR-swizzled float4 slots

    const int b = blockIdx.z, h = blockIdx.y;
    const int q0 = blockIdx.x * 32;
    const int t = threadIdx.x;
    const float* qb = qh + (size_t)(b * HN + h) * SEQ * DH;
    const float* kb = kh + (size_t)(b * HN + h) * SEQ * DH;

    for (int p = t; p < 32 * 64; p += 256) {
        int r = p >> 6, d = p & 63;
        int arow = q0 + r;
        float v = 0.f;
        if (arow <= SM1 - 1) v = qb[(size_t)(arow + 1) * DH + d];
        qs[r * 68 + d] = v;
    }

    const int tq = t >> 5;   // 0..7
    const int tk = t & 31;   // 0..31

    for (int kt = 0; kt < 8; ++kt) {
        const int kstart = kt * 128;
        __syncthreads();
        for (int p = t; p < 128 * 64; p += 256) {
            int r = p >> 6, d = p & 63;
            int krow = kstart + r;
            float v = (krow <= SM1 - 1) ? kb[(size_t)krow * DH + d] : 0.f;
            int s = d >> 2;
            ks[r * 64 + (((s ^ (r & 15)) << 2) | (d & 3))] = v;
        }
        __syncthreads();

        float acc[4][4] = {};
#pragma unroll 4
        for (int d0 = 0; d0 < 64; d0 += 4) {
            float4 qv[4], kv[4];
            int s = d0 >> 2;
#pragma unroll
            for (int i = 0; i < 4; ++i)
                qv[i] = *(const float4*)&qs[(tq + 8 * i) * 68 + d0];
#pragma unroll
            for (int j = 0; j < 4; ++j) {
                int r = tk + 32 * j;
                kv[j] = *(const float4*)&ks[r * 64 + ((s ^ (r & 15)) << 2)];
            }
#pragma unroll
            for (int i = 0; i < 4; ++i)
#pragma unroll
                for (int j = 0; j < 4; ++j)
                    acc[i][j] += qv[i].x * kv[j].x + qv[i].y * kv[j].y +
                                 qv[i].z * kv[j].z + qv[i].w * kv[j].w;
        }

#pragma unroll
        for (int i = 0; i < 4; ++i) {
            int arow = q0 + tq + 8 * i;
            if (arow > SM1 - 1) continue;
            size_t rbase = ((size_t)(b * HN + h) * SM1 + arow) * SM1;
            size_t mbase = ((size_t)b * SM1 + arow) * SM1;
#pragma unroll
            for (int j = 0; j < 4; ++j) {
                int kk = kstart + tk + 32 * j;
                if (kk > SM1 - 1) continue;
                float sc = fmaxf(acc[i][j] * 0.125f, 0.f);
                if (mask[mbase + kk]) sc -= 1e9f;
                att[rbase + kk] = sc;
            }
        }
    }
}

// ---------------------------------------------------------------
// Kernel C: softmax over logits (in-place -> normalized weights in
// att region) + PV into ctx[b][row][h*64+d].
// 8 q-rows per block, 256 threads.
// ---------------------------------------------------------------
__global__ __launch_bounds__(256)
void softmax_pv_kernel(float* __restrict__ att, const float* __restrict__ vh,
                       float* __restrict__ ctx)
{
    __shared__ float wt[8][SM1];
    __shared__ float red[4][8][64];

    const int b = blockIdx.z, h = blockIdx.y;
    const int q0 = blockIdx.x * 8;
    const int t = threadIdx.x;
    const int nrows = min(8, SM1 - q0);
    const size_t abase = ((size_t)(b * HN + h) * SM1 + q0) * SM1;

    for (int r = 0; r < nrows; ++r)
        for (int c = t; c < SM1; c += 256)
            wt[r][c] = att[abase + (size_t)r * SM1 + c];
    __syncthreads();

    const int w = t >> 6, lane = t & 63;
#pragma unroll
    for (int rr = 0; rr < 2; ++rr) {
        int r = w * 2 + rr;
        if (r < nrows) {
            float vreg[16];
            float m = -1e30f;
#pragma unroll
            for (int i = 0; i < 16; ++i) {
                int c = lane + 64 * i;
                float v = (c < SM1) ? wt[r][c] : -1e30f;
                vreg[i] = v;
                m = fmaxf(m, v);
            }
            for (int off = 32; off; off >>= 1) m = fmaxf(m, __shfl_xor(m, off, 64));
            float sum = 0.f;
#pragma unroll
            for (int i = 0; i < 16; ++i) {
                int c = lane + 64 * i;
                if (c < SM1) { vreg[i] = expf(vreg[i] - m); sum += vreg[i]; }
            }
            for (int off = 32; off; off >>= 1) sum += __shfl_xor(sum, off, 64);
            float inv = 1.0f / sum;
#pragma unroll
            for (int i = 0; i < 16; ++i) {
                int c = lane + 64 * i;
                if (c < SM1) {
                    float wv = vreg[i] * inv;
                    wt[r][c] = wv;
                    att[abase + (size_t)r * SM1 + c] = wv;
                }
            }
        }
    }
    __syncthreads();

    // PV: waves split the key range; thread = (d4, qg) covers 2 rows.
    const int d4 = t & 15, qg = (t >> 4) & 3;
    const float* vb = vh + (size_t)(b * HN + h) * SM1 * DH;
    float4 acc0 = {0,0,0,0}, acc1 = {0,0,0,0};
    const int k0 = w * 256, k1 = min(SM1, k0 + 256);
    for (int k = k0; k < k1; ++k) {
        float4 vv = *(const float4*)&vb[(size_t)k * DH + d4 * 4];
        float w0 = wt[qg * 2][k], w1 = wt[qg * 2 + 1][k];
        acc0.x += w0 * vv.x; acc0.y += w0 * vv.y; acc0.z += w0 * vv.z; acc0.w += w0 * vv.w;
        acc1.x += w1 * vv.x; acc1.y += w1 * vv.y; acc1.z += w1 * vv.z; acc1.w += w1 * vv.w;
    }
    *(float4*)&red[w][qg * 2][d4 * 4] = acc0;
    *(float4*)&red[w][qg * 2 + 1][d4 * 4] = acc1;
    __syncthreads();

    for (int idx = t; idx < 8 * 64; idx += 256) {
        int qi = idx >> 6, d = idx & 63;
        if (qi < nrows) {
            float s = red[0][qi][d] + red[1][qi][d] + red[2][qi][d] + red[3][qi][d];
            ctx[((size_t)b * SM1 + q0 + qi) * DMODEL + h * DH + d] = s;
        }
    }
}

// ---------------------------------------------------------------
extern "C" void kernel_launch(void* const* d_in, const int* in_sizes, int n_in,
                              void* d_out, int out_size, void* d_ws, size_t ws_size,
                              hipStream_t stream) {
    const float* q    = (const float*)d_in[0];
    const float* k    = (const float*)d_in[1];
    const float* v    = (const float*)d_in[2];
    const int*   mask = (const int*)  d_in[4];
    const float* Wq   = (const float*)d_in[5];
    const float* bq   = (const float*)d_in[6];
    const float* Wk   = (const float*)d_in[7];
    const float* bk   = (const float*)d_in[8];
    const float* Wv   = (const float*)d_in[9];
    const float* bv   = (const float*)d_in[10];
    const float* Wo   = (const float*)d_in[11];
    const float* bo   = (const float*)d_in[12];

    float* out0 = (float*)d_out;                       // [2,1023,1024]
    float* att  = out0 + (size_t)2 * SM1 * DMODEL;     // [2,16,1023,1023]

    float* ws  = (float*)d_ws;
    float* qh  = ws;                                   // [2,16,1024,64]
    float* kh  = qh + (size_t)2 * HN * SEQ * DH;       // [2,16,1024,64]
    float* vh  = kh + (size_t)2 * HN * SEQ * DH;       // [2,16,1023,64]
    float* ctx = vh + (size_t)2 * HN * SM1 * DH;       // [2,1023,1024]

    gemm64_kernel<0><<<dim3(16, 32), 256, 0, stream>>>(q, Wq, bq, qh, 2 * SEQ, SEQ);
    gemm64_kernel<0><<<dim3(16, 32), 256, 0, stream>>>(k, Wk, bk, kh, 2 * SEQ, SEQ);
    gemm64_kernel<0><<<dim3(16, 32), 256, 0, stream>>>(v, Wv, bv, vh, 2 * SM1, SM1);

    qk_kernel<<<dim3(32, HN, 2), 256, 0, stream>>>(qh, kh, mask, att);
    softmax_pv_kernel<<<dim3(128, HN, 2), 256, 0, stream>>>(att, vh, ctx);

    gemm64_kernel<1><<<dim3(16, 32), 256, 0, stream>>>(ctx, Wo, bo, out0, 2 * SM1, SM1);
}